// Round 16
// baseline (363.816 us; speedup 1.0000x reference)
//
#include <hip/hip_runtime.h>

#define KW 11
#define PAD 5
#define TW 64              // tile width (halo overhead 74/64 = 1.16x)
#define TH 32              // two strips of 16 rows (R14: depth-4 regressed)
#define HROWS 16           // rows per strip (phase B row r needs only vv row r)
#define ICOLS 74           // input col span incl. halo (TW + KW - 1)
#define S4 77              // f4-plane row stride
#define SX 78              // sx-plane row stride (EVEN -> f2-aligned B reads)
#define IMH 512
#define IMW 512
#define NBLK 6144          // 8 x 16 x 48
#define NCONV 296          // ICOLS*4 phase-A conv tasks
#define LBASE 320          // loader threads start (wave-aligned: waves 5..7)
#define NLOAD 192          // loader thread count
#define RAWROWS 26         // strip-1 input rows union (16 out + 10 halo)
#define RAWV (2*RAWROWS*74)   // 3848 raw values (img-interleaved)
#define LTASK 21           // ceil(3848/192)

typedef float f2 __attribute__((ext_vector_type(2)));
typedef float f4 __attribute__((ext_vector_type(4)));

// LDS: vv4[row*S4+col] = (mu1,mu2,q11,q22) f4; vsx = x1*x2; raw = strip-1
// input, img-interleaved raw[2*(row*74+col)+img].
// Schedule: convs(t<296): A0.load(reg) -> A0.conv | loaders(t>=320): raw
// load -> LDS | bar | B0(all) | bar | A1.conv reads raw | bar | B1 | reduce.
//
// R6: reg-hoisted loads (MLP) = the lever. R8: never DEMAND occupancy
// (min-waves spill disaster); WRITE_SIZE > ~1 MB = spill alarm.
// R10: compiler sinks same-thread prefetch -> cross-thread staging (R13).
// R12: bank-conflict counter ~constant, benign. R13: producer-wave staging
// -> 71.3 us. R14: depth-4 regressed (phase-aligned troughs); depth 2 right.
// R15: SX=78 even -> b64 sx reads, 69.5 us.
// R16: fold final reduction into ssim_main: per-block f64 atomicAdd into
// d_ws (order-independent to 2^-52 -> deterministic), last-ticket block
// writes out[0]. Kills the ssim_reduce launch (~10-20 us of measured path).

#define A_LOAD(EDGE_)                                                         \
    if (t < NCONV) {                                                          \
        const int gr0 = iy0 + ar0;                                            \
        if (EDGE_) {                                                          \
            const bool cok = (agc >= 0) && (agc < IMW);                       \
            _Pragma("unroll")                                                 \
            for (int i = 0; i < 14; ++i) {                                    \
                const int gr = gr0 + i;                                       \
                const bool ok = cok && (gr >= 0) && (gr < IMH);               \
                const size_t o = base + (size_t)(ok ? gr : 0) * IMW           \
                               + (ok ? agc : 0);                              \
                p1[i] = ok ? img1[o] : 0.f;                                   \
                p2[i] = ok ? img2[o] : 0.f;                                   \
            }                                                                 \
        } else {                                                              \
            _Pragma("unroll")                                                 \
            for (int i = 0; i < 14; ++i) {                                    \
                const size_t o = base + (size_t)(gr0 + i) * IMW + agc;        \
                p1[i] = img1[o];                                              \
                p2[i] = img2[o];                                              \
            }                                                                 \
        }                                                                     \
    }

// Loaders: 21 tasks each, o = lidx + 192*s; img = o&1 (per-thread constant
// since 192 even), row = o/148, col = (o%148)>>1. Only s==20 can exceed RAWV.
#define RAW_STAGE(EDGE_)                                                      \
    {                                                                         \
        float rv[LTASK];                                                      \
        _Pragma("unroll")                                                     \
        for (int s = 0; s < LTASK; ++s) {                                     \
            const int o = lidx + NLOAD * s;                                   \
            const int row = o / 148;                                          \
            const int col = (o % 148) >> 1;                                   \
            const int gr = iy1 + row;       /* iy1 >= 11: no top check */     \
            const int gc = ix0 + col;                                         \
            const float* sp = (o & 1) ? img2 : img1;                          \
            bool ok = (s != LTASK - 1) || (o < RAWV);                         \
            if (EDGE_) ok = ok && (gr < IMH) && (gc >= 0) && (gc < IMW);      \
            const size_t go = base + (size_t)(ok ? gr : 0) * IMW              \
                            + (ok ? gc : 0);                                  \
            rv[s] = ok ? sp[go] : 0.f;                                        \
        }                                                                     \
        _Pragma("unroll")                                                     \
        for (int s = 0; s < LTASK; ++s) {                                     \
            const int o = lidx + NLOAD * s;                                   \
            if (s != LTASK - 1 || o < RAWV) raw[o] = rv[s];                   \
        }                                                                     \
    }

// Shared conv body: consumes x12 (f2 per row i), writes vv4/vsx.
#define A_CONV_BODY(GETX_)                                                    \
    {                                                                         \
        f2 m12[4]  = {{0,0},{0,0},{0,0},{0,0}};                               \
        f2 qq[4]   = {{0,0},{0,0},{0,0},{0,0}};                               \
        f2 sx01 = {0, 0}, sx23 = {0, 0};                                      \
        _Pragma("unroll")                                                     \
        for (int i = 0; i < 14; ++i) {                                        \
            f2 x12; GETX_;                                                    \
            const f2 sq = x12 * x12;                                          \
            const float sxy = x12.x * x12.y;                                  \
            f2 sxy2; sxy2.x = sxy; sxy2.y = sxy;                              \
            _Pragma("unroll")                                                 \
            for (int k = 0; k < 4; ++k) {                                     \
                const int j = i - k;                                          \
                if (j >= 0 && j < KW) {                                       \
                    const float w = wg[j];   /* SGPR operand */               \
                    const f2 w2 = {w, w};                                     \
                    m12[k] += w2 * x12;          /* v_pk_fma_f32 */           \
                    qq[k]  += w2 * sq;           /* v_pk_fma_f32 */           \
                }                                                             \
            }                                                                 \
            if (i >= 1 && i <= 10)       sx01 += wp[i] * sxy2;                \
            else if (i == 0)             sx01.x += wg[0]  * sxy;              \
            else if (i == 11)            sx01.y += wg[10] * sxy;              \
            if (i >= 3 && i <= 12)       sx23 += wp[i - 2] * sxy2;            \
            else if (i == 2)             sx23.x += wg[0]  * sxy;              \
            else if (i == 13)            sx23.y += wg[10] * sxy;              \
        }                                                                     \
        const float sxs[4] = {sx01.x, sx01.y, sx23.x, sx23.y};                \
        _Pragma("unroll")                                                     \
        for (int k = 0; k < 4; ++k) {                                         \
            f4 v;                                                             \
            v.x = m12[k].x; v.y = m12[k].y;                                   \
            v.z = qq[k].x;  v.w = qq[k].y;                                    \
            vv4[(ar0 + k) * S4 + ac] = v;        /* ds_write_b128 */          \
            vsx[(ar0 + k) * SX + ac] = sxs[k];   /* ds_write_b32  */          \
        }                                                                     \
    }

// Phase B: 2 output cols per thread, row = t&15, cp = t>>4; packed-wt sx.
// sx plane read as 6 f2 (b64): base word 78*row + 2*cp is EVEN -> aligned.
#define PHASE_B(H_)                                                           \
    {                                                                         \
        const int row = t & 15;                                               \
        const int cp  = t >> 4;              /* 0..31 */                      \
        const f4* __restrict__ p4 = &vv4[row * S4 + cp * 2];                  \
        const f2* __restrict__ px2 =                                          \
            reinterpret_cast<const f2*>(&vsx[row * SX + cp * 2]);             \
        f2 am12[2] = {{0,0},{0,0}};                                           \
        f2 aqq[2]  = {{0,0},{0,0}};                                           \
        f2 asxp = {0, 0};                                                     \
        _Pragma("unroll")                                                     \
        for (int b = 0; b < 3; ++b) {                                         \
            f4 v[4]; f2 vp[2];                                                \
            _Pragma("unroll")                                                 \
            for (int cc = 0; cc < 4; ++cc) v[cc] = p4[b * 4 + cc];            \
            vp[0] = px2[b * 2];                                               \
            vp[1] = px2[b * 2 + 1];                                           \
            _Pragma("unroll")                                                 \
            for (int cc = 0; cc < 4; ++cc) {                                  \
                const int cg = b * 4 + cc;                                    \
                const float vxc = (cc & 1) ? vp[cc >> 1].y : vp[cc >> 1].x;   \
                f2 v12; v12.x = v[cc].x; v12.y = v[cc].y;                     \
                f2 vqq; vqq.x = v[cc].z; vqq.y = v[cc].w;                     \
                _Pragma("unroll")                                             \
                for (int k = 0; k < 2; ++k) {                                 \
                    const int j = cg - k;                                     \
                    if (j >= 0 && j < KW) {                                   \
                        const float w = wg[j];                                \
                        const f2 w2 = {w, w};                                 \
                        am12[k] += w2 * v12;                                  \
                        aqq[k]  += w2 * vqq;                                  \
                    }                                                         \
                }                                                             \
                f2 vx2; vx2.x = vxc; vx2.y = vxc;                             \
                if (cg >= 1 && cg <= 10)  asxp += wp[cg] * vx2;               \
                else if (cg == 0)         asxp.x += wg[0]  * vxc;             \
                else if (cg == 11)        asxp.y += wg[10] * vxc;             \
            }                                                                 \
        }                                                                     \
        const float asx[2] = {asxp.x, asxp.y};                                \
        _Pragma("unroll")                                                     \
        for (int k = 0; k < 2; ++k) {                                         \
            const float mu1 = am12[k].x, mu2 = am12[k].y;                     \
            const float mu1sq = mu1 * mu1, mu2sq = mu2 * mu2;                 \
            const float mu12 = mu1 * mu2;                                     \
            const float sig1 = aqq[k].x - mu1sq;                              \
            const float sig2 = aqq[k].y - mu2sq;                              \
            const float sig12 = asx[k] - mu12;                                \
            const float num = (2.f * mu12 + C1v) * (2.f * sig12 + C2v);       \
            const float den = (mu1sq + mu2sq + C1v) * (sig1 + sig2 + C2v);    \
            float r = __builtin_amdgcn_rcpf(den);                             \
            r = r * (2.f - den * r);             /* Newton -> ~fp32 exact */  \
            lsum += num * r;                                                  \
        }                                                                     \
    }

__global__ __launch_bounds__(512, 4) void ssim_main(
    const float* __restrict__ img1, const float* __restrict__ img2,
    const float* __restrict__ window, float* __restrict__ out,
    double* __restrict__ dsum, unsigned* __restrict__ cnt, double inv_n)
{
    __shared__ f4 vv4[HROWS * S4];                      // 19712 B
    __shared__ __align__(16) float vsx[HROWS * SX];     //  4992 B
    __shared__ __align__(16) float raw[RAWV];           // 15392 B -> ~40.2 KB
    __shared__ float g[KW];
    __shared__ float wsum[8];

    const int t = threadIdx.x;

    const int plane = blockIdx.z;
    const size_t base = (size_t)plane * IMH * IMW;
    const int ix0 = blockIdx.x * TW - PAD;
    const int iy0 = blockIdx.y * TH - PAD;
    const int iy1 = iy0 + HROWS;                  // first strip-1 input row

    const int ac  = t % ICOLS;                    // conv col (valid t < NCONV)
    const int ar0 = (t / ICOLS) * 4;              // conv local row base
    const int agc = ix0 + ac;
    const int lidx = t - LBASE;                   // loader index (t >= LBASE)

    const bool interior = (ix0 >= 0) && (ix0 + ICOLS <= IMW) &&
                          (iy0 >= 0) && (iy0 + TH + KW - 1 <= IMH);

    float p1[14], p2[14];                         // strip-0 reg inputs (conv)

    // Conv threads issue strip-0 loads; loader waves (5..7) stage strip 1.
    if (t < LBASE) {
        if (interior) { A_LOAD(false) } else { A_LOAD(true) }
    } else {
        if (interior) { RAW_STAGE(false) } else { RAW_STAGE(true) }
    }

    // Separable 1D Gaussian = row-sums of the 2D window (columns sum to 1).
    if (t < KW) {
        float s = 0.f;
        for (int j = 0; j < KW; ++j) s += window[(t * KW + j) * 3];
        g[t] = s;
    }
    __syncthreads();

    // Weights wave-uniform -> SGPRs (VALU reads one SGPR operand free).
    float wg[KW];
#pragma unroll
    for (int j = 0; j < KW; ++j) {
        const int bi = __builtin_amdgcn_readfirstlane(__float_as_int(g[j]));
        wg[j] = __int_as_float(bi);
    }
    // Packed weight pairs wp[j] = {w[j], w[j-1]} for pk-fma sx accumulation.
    f2 wp[KW];
#pragma unroll
    for (int j = 1; j < KW; ++j) { wp[j].x = wg[j]; wp[j].y = wg[j - 1]; }

    const float C1v = 0.0001f;
    const float C2v = 0.0009f;
    float lsum = 0.f;

    // ---- Strip 0 conv (from regs) ----
    if (t < NCONV) A_CONV_BODY(x12.x = p1[i]; x12.y = p2[i];)
    __syncthreads();

    PHASE_B(0)
    __syncthreads();

    // ---- Strip 1 conv (from raw LDS: f2 img-interleaved reads) ----
    if (t < NCONV)
        A_CONV_BODY(x12 = *reinterpret_cast<const f2*>(
                        &raw[((ar0 + i) * 74 + ac) * 2]);)
    __syncthreads();

    PHASE_B(1)

    // ---- Reduction: wave shuffle -> cross-wave LDS -> f64 atomic ----
#pragma unroll
    for (int off = 32; off > 0; off >>= 1) lsum += __shfl_down(lsum, off, 64);
    if ((t & 63) == 0) wsum[t >> 6] = lsum;
    __syncthreads();
    if (t == 0) {
        float bs = 0.f;
#pragma unroll
        for (int w = 0; w < 8; ++w) bs += wsum[w];
        atomicAdd(dsum, (double)bs);              // f64: order-independent
        __threadfence();                          // dsum-add before ticket
        const unsigned ticket = atomicAdd(cnt, 1u);
        if (ticket == NBLK - 1) {                 // last block finishes
            const double tot = atomicAdd(dsum, 0.0);   // coherent read
            out[0] = (float)(tot * inv_n);
        }
    }
}

extern "C" void kernel_launch(void* const* d_in, const int* in_sizes, int n_in,
                              void* d_out, int out_size, void* d_ws, size_t ws_size,
                              hipStream_t stream) {
    const float* img1   = (const float*)d_in[0];
    const float* img2   = (const float*)d_in[1];
    const float* window = (const float*)d_in[2];
    float* out = (float*)d_out;
    double* dsum = (double*)d_ws;                // [0]: f64 accumulator
    unsigned* cnt = (unsigned*)((char*)d_ws + 8);// [8..11]: ticket counter

    const int nplanes = in_sizes[0] / (IMH * IMW);   // 48
    const long long total = (long long)in_sizes[0];

    hipMemsetAsync(d_ws, 0, 16, stream);         // zero dsum + cnt (captured)

    dim3 grid(IMW / TW, IMH / TH, nplanes);      // 8 x 16 x 48 = 6144
    ssim_main<<<grid, 512, 0, stream>>>(img1, img2, window, out,
                                        dsum, cnt, 1.0 / (double)total);
}